// Round 1
// baseline (305.882 us; speedup 1.0000x reference)
//
#include <hip/hip_runtime.h>

// PosEncoding: coords [1, N, 3] f32 -> out [1, N, 63] f32
// out[n][0:3]            = coords[n][0:3]
// out[n][3 + i*6 + j*2]  = sin(coords[n][j] * 2^i * pi)   i=0..9, j=0..2
// out[n][3 + i*6 + j*2+1]= cos(coords[n][j] * 2^i * pi)
//
// Angle in REVOLUTIONS: c * 2^i * pi rad == c * 2^(i-1) rev (exact via ldexp).
// v_sin_f32 / v_cos_f32 take revolutions; fract() range-reduces exactly.

__global__ __launch_bounds__(256) void posenc_kernel(
    const float* __restrict__ coords,
    float* __restrict__ out,
    int total)   // total = N * 63
{
    const int stride = (int)(gridDim.x * blockDim.x);
    for (int idx = (int)(blockIdx.x * blockDim.x + threadIdx.x);
         idx < total; idx += stride) {
        const unsigned u  = (unsigned)idx;
        const unsigned n  = u / 63u;          // point index  (magic-mul)
        const unsigned k  = u - n * 63u;      // element within point, 0..62

        float val;
        if (k < 3u) {
            val = coords[n * 3u + k];
        } else {
            const unsigned kk  = k - 3u;      // 0..59
            const unsigned fi  = kk / 6u;     // frequency index 0..9
            const unsigned rem = kk - fi * 6u;// 0..5
            const unsigned j   = rem >> 1;    // feature 0..2

            const float c  = coords[n * 3u + j];
            const float r  = ldexpf(c, (int)fi - 1);  // c * 2^(fi-1) rev, exact
            const float fr = r - floorf(r);           // [0,1) — exact reduction
            val = (rem & 1u) ? __builtin_amdgcn_cosf(fr)
                             : __builtin_amdgcn_sinf(fr);
        }
        out[idx] = val;
    }
}

extern "C" void kernel_launch(void* const* d_in, const int* in_sizes, int n_in,
                              void* d_out, int out_size, void* d_ws, size_t ws_size,
                              hipStream_t stream) {
    const float* coords = (const float*)d_in[0];
    float* out = (float*)d_out;

    const int n_points = in_sizes[0] / 3;     // 2,097,152
    const int total    = n_points * 63;       // 132,120,576 (== out_size)

    const int block = 256;
    const int grid  = 2048;                   // grid-stride; 32 waves/CU
    posenc_kernel<<<grid, block, 0, stream>>>(coords, out, total);
}

// Round 2
// 106.400 us; speedup vs baseline: 2.8748x; 2.8748x over previous
//
#include <hip/hip_runtime.h>

// PosEncoding: coords [1, N, 3] f32 -> out [1, N, 63] f32
// out[n][0:3]             = coords[n][0:3]
// out[n][3 + i*6 + j*2]   = sin(coords[n][j] * 2^i * pi)   i=0..9, j=0..2
// out[n][3 + i*6 + j*2+1] = cos(coords[n][j] * 2^i * pi)
//
// Angle in REVOLUTIONS: c * 2^i * pi rad == c * 2^(i-1) rev.
// r starts at c*0.5 (exact), doubles each freq (exact); fract() reduces to
// [0,1); v_sin_f32/v_cos_f32 take revolutions.
//
// Structure: 1 thread = 1 point. Compute 63 outputs into LDS (no divides,
// no divergence), then block-cooperative float4 copy-out (coalesced stores).

#define NPTS_PER_BLOCK 256
#define OUT_PER_POINT  63
#define TILE_FLOATS    (NPTS_PER_BLOCK * OUT_PER_POINT)  // 16128
#define TILE_V4        (TILE_FLOATS / 4)                 // 4032

__global__ __launch_bounds__(256) void posenc_kernel(
    const float* __restrict__ coords,
    float4* __restrict__ out4,
    int n_points)
{
    __shared__ float4 lds4[TILE_V4];
    float* lds = (float*)lds4;

    const int t = (int)threadIdx.x;
    const int p = (int)blockIdx.x * NPTS_PER_BLOCK + t;

    // ---- phase 1: compute this thread's point into LDS ----
    if (p < n_points) {
        const float c0 = coords[p * 3 + 0];
        const float c1 = coords[p * 3 + 1];
        const float c2 = coords[p * 3 + 2];

        float* o = &lds[t * OUT_PER_POINT];
        o[0] = c0; o[1] = c1; o[2] = c2;

        // revolutions for freq i: c * 2^(i-1)
        float r0 = c0 * 0.5f, r1 = c1 * 0.5f, r2 = c2 * 0.5f;

        int k = 3;
        #pragma unroll
        for (int i = 0; i < 10; ++i) {
            const float f0 = r0 - floorf(r0);
            const float f1 = r1 - floorf(r1);
            const float f2 = r2 - floorf(r2);
            o[k + 0] = __builtin_amdgcn_sinf(f0);
            o[k + 1] = __builtin_amdgcn_cosf(f0);
            o[k + 2] = __builtin_amdgcn_sinf(f1);
            o[k + 3] = __builtin_amdgcn_cosf(f1);
            o[k + 4] = __builtin_amdgcn_sinf(f2);
            o[k + 5] = __builtin_amdgcn_cosf(f2);
            k += 6;
            r0 *= 2.0f; r1 *= 2.0f; r2 *= 2.0f;  // exact doubling
        }
    }
    __syncthreads();

    // ---- phase 2: coalesced float4 copy-out ----
    const int gbase = (int)blockIdx.x * TILE_V4;
    for (int v = t; v < TILE_V4; v += NPTS_PER_BLOCK) {
        out4[gbase + v] = lds4[v];
    }
}

extern "C" void kernel_launch(void* const* d_in, const int* in_sizes, int n_in,
                              void* d_out, int out_size, void* d_ws, size_t ws_size,
                              hipStream_t stream) {
    const float* coords = (const float*)d_in[0];
    float4* out4 = (float4*)d_out;

    const int n_points = in_sizes[0] / 3;                       // 2,097,152
    const int grid = (n_points + NPTS_PER_BLOCK - 1) / NPTS_PER_BLOCK;  // 8192

    posenc_kernel<<<grid, NPTS_PER_BLOCK, 0, stream>>>(coords, out4, n_points);
}

// Round 4
// 101.615 us; speedup vs baseline: 3.0102x; 1.0471x over previous
//
#include <hip/hip_runtime.h>

// PosEncoding: coords [1, N, 3] f32 -> out [1, N, 63] f32
// out[n][0:3]             = coords[n][0:3]
// out[n][3 + i*6 + j*2]   = sin(coords[n][j] * 2^i * pi)   i=0..9, j=0..2
// out[n][3 + i*6 + j*2+1] = cos(coords[n][j] * 2^i * pi)
//
// Angle in REVOLUTIONS: c * 2^i * pi rad == c * 2^(i-1) rev.
// r starts at c*0.5 (exact), doubles each freq (exact); fract() reduces to
// [0,1); v_sin_f32/v_cos_f32 take revolutions.
//
// Structure: 1 thread = 1 point; each WAVE is an independent pipeline:
// it computes its 64 points into a private LDS slice, then immediately
// copies its own contiguous 16128 B range to global (nontemporal f32x4).
// No __syncthreads — same-wave LDS ordering via lgkmcnt is sufficient.

typedef float f32x4 __attribute__((ext_vector_type(4)));  // native vec: ok for
                                                          // __builtin_nontemporal_store

#define BLOCK_THREADS  256
#define WAVE_PTS       64
#define OUT_PER_POINT  63
#define WAVE_FLOATS    (WAVE_PTS * OUT_PER_POINT)        // 4032
#define WAVE_V4        (WAVE_FLOATS / 4)                 // 1008
#define BLOCK_V4       (WAVE_V4 * (BLOCK_THREADS / 64))  // 4032

__global__ __launch_bounds__(BLOCK_THREADS) void posenc_kernel(
    const float* __restrict__ coords,
    f32x4* __restrict__ out4,
    int n_points)
{
    __shared__ f32x4 lds4[BLOCK_V4];
    float* lds = (float*)lds4;

    const int t    = (int)threadIdx.x;
    const int wave = t >> 6;          // 0..3
    const int lane = t & 63;
    const int p    = (int)blockIdx.x * BLOCK_THREADS + t;   // this thread's point

    // ---- phase 1: compute this thread's point into the wave's LDS slice ----
    if (p < n_points) {
        const float c0 = coords[p * 3 + 0];
        const float c1 = coords[p * 3 + 1];
        const float c2 = coords[p * 3 + 2];

        float* o = &lds[(wave * WAVE_PTS + lane) * OUT_PER_POINT];
        o[0] = c0; o[1] = c1; o[2] = c2;

        // revolutions for freq i: c * 2^(i-1)
        float r0 = c0 * 0.5f, r1 = c1 * 0.5f, r2 = c2 * 0.5f;

        int k = 3;
        #pragma unroll
        for (int i = 0; i < 10; ++i) {
            const float f0 = r0 - floorf(r0);
            const float f1 = r1 - floorf(r1);
            const float f2 = r2 - floorf(r2);
            o[k + 0] = __builtin_amdgcn_sinf(f0);
            o[k + 1] = __builtin_amdgcn_cosf(f0);
            o[k + 2] = __builtin_amdgcn_sinf(f1);
            o[k + 3] = __builtin_amdgcn_cosf(f1);
            o[k + 4] = __builtin_amdgcn_sinf(f2);
            o[k + 5] = __builtin_amdgcn_cosf(f2);
            k += 6;
            r0 *= 2.0f; r1 *= 2.0f; r2 *= 2.0f;  // exact doubling
        }
    }

    // ---- phase 2: this wave copies its own slice out (coalesced, nt) ----
    // wave's global f32x4 base: (blk*256 + wave*64)*63/4
    const long long gbase = (long long)blockIdx.x * BLOCK_V4 + wave * WAVE_V4;
    const long long gmax  = (long long)n_points * OUT_PER_POINT / 4;
    const int lbase = wave * WAVE_V4;

    #pragma unroll
    for (int it = 0; it < (WAVE_V4 + 63) / 64; ++it) {
        const int v = it * 64 + lane;
        if (v < WAVE_V4 && gbase + v < gmax) {
            __builtin_nontemporal_store(lds4[lbase + v], &out4[gbase + v]);
        }
    }
}

extern "C" void kernel_launch(void* const* d_in, const int* in_sizes, int n_in,
                              void* d_out, int out_size, void* d_ws, size_t ws_size,
                              hipStream_t stream) {
    const float* coords = (const float*)d_in[0];
    f32x4* out4 = (f32x4*)d_out;

    const int n_points = in_sizes[0] / 3;                            // 2,097,152
    const int grid = (n_points + BLOCK_THREADS - 1) / BLOCK_THREADS; // 8192

    posenc_kernel<<<grid, BLOCK_THREADS, 0, stream>>>(coords, out4, n_points);
}

// Round 5
// 99.735 us; speedup vs baseline: 3.0669x; 1.0188x over previous
//
#include <hip/hip_runtime.h>

// PosEncoding: coords [1, N, 3] f32 -> out [1, N, 63] f32
// out[n][0:3]             = coords[n][0:3]
// out[n][3 + i*6 + j*2]   = sin(coords[n][j] * 2^i * pi)   i=0..9, j=0..2
// out[n][3 + i*6 + j*2+1] = cos(coords[n][j] * 2^i * pi)
//
// Angle in REVOLUTIONS: c * 2^i * pi rad == c * 2^(i-1) rev (exact doubling).
// fract() reduces to [0,1); v_sin_f32/v_cos_f32 take revolutions.
//
// Structure: 1-wave (64-thread) blocks, each an independent pipeline:
//   phase 0: cooperative aligned f32x4 load of the wave's 768 B coord panel
//            into LDS staging (each 64B line fetched exactly once — fixes the
//            2x read over-fetch seen with 3 scalar dword loads/lane),
//   phase 1: per-thread compute of one point's 63 outputs into the LDS tile,
//   phase 2: coalesced f32x4 copy-out of the wave's contiguous 16128 B range.
// LDS = 16896 B/block -> ~9 blocks/CU = 9 independent pipelines per CU.
// Plain (non-nt) stores this round: A/B vs round-4's nontemporal.

typedef float f32x4 __attribute__((ext_vector_type(4)));

#define BLOCK_THREADS  64
#define WAVE_PTS       64
#define OUT_PER_POINT  63
#define WAVE_FLOATS    (WAVE_PTS * OUT_PER_POINT)   // 4032
#define WAVE_V4        (WAVE_FLOATS / 4)            // 1008
#define CSTAGE_V4      (WAVE_PTS * 3 / 4)           // 48 (768 B)

__global__ __launch_bounds__(BLOCK_THREADS) void posenc_kernel(
    const float* __restrict__ coords,
    f32x4* __restrict__ out4,
    int n_points)
{
    __shared__ f32x4 tile4[WAVE_V4];
    __shared__ f32x4 cstage4[CSTAGE_V4];
    float* tile   = (float*)tile4;
    float* cstage = (float*)cstage4;

    const int lane = (int)threadIdx.x;
    const long long pbase = (long long)blockIdx.x * WAVE_PTS;

    // ---- phase 0: cooperative aligned coord load (768 B per wave) ----
    {
        const long long in_v4 = (long long)n_points * 3 / 4;  // total f32x4 in coords
        const long long cb    = (long long)blockIdx.x * CSTAGE_V4;
        if (lane < CSTAGE_V4 && cb + lane < in_v4) {
            cstage4[lane] = ((const f32x4*)coords)[cb + lane];
        }
    }
    __syncthreads();   // 1-wave block: near-free, guarantees LDS ordering

    // ---- phase 1: compute this thread's point into the LDS tile ----
    if (pbase + lane < n_points) {
        const float c0 = cstage[lane * 3 + 0];
        const float c1 = cstage[lane * 3 + 1];
        const float c2 = cstage[lane * 3 + 2];

        float* o = &tile[lane * OUT_PER_POINT];
        o[0] = c0; o[1] = c1; o[2] = c2;

        // revolutions for freq i: c * 2^(i-1)
        float r0 = c0 * 0.5f, r1 = c1 * 0.5f, r2 = c2 * 0.5f;

        int k = 3;
        #pragma unroll
        for (int i = 0; i < 10; ++i) {
            const float f0 = r0 - floorf(r0);
            const float f1 = r1 - floorf(r1);
            const float f2 = r2 - floorf(r2);
            o[k + 0] = __builtin_amdgcn_sinf(f0);
            o[k + 1] = __builtin_amdgcn_cosf(f0);
            o[k + 2] = __builtin_amdgcn_sinf(f1);
            o[k + 3] = __builtin_amdgcn_cosf(f1);
            o[k + 4] = __builtin_amdgcn_sinf(f2);
            o[k + 5] = __builtin_amdgcn_cosf(f2);
            k += 6;
            r0 *= 2.0f; r1 *= 2.0f; r2 *= 2.0f;  // exact doubling
        }
    }
    __syncthreads();

    // ---- phase 2: coalesced f32x4 copy-out (contiguous 16128 B) ----
    const long long gbase = (long long)blockIdx.x * WAVE_V4;
    const long long gmax  = (long long)n_points * OUT_PER_POINT / 4;

    if (gbase + WAVE_V4 <= gmax) {           // full block: unguarded fast path
        #pragma unroll
        for (int it = 0; it < WAVE_V4 / 64; ++it)          // 15 full iters
            out4[gbase + it * 64 + lane] = tile4[it * 64 + lane];
        if (lane < (WAVE_V4 & 63))                          // 48-lane tail
            out4[gbase + (WAVE_V4 / 64) * 64 + lane] = tile4[(WAVE_V4 / 64) * 64 + lane];
    } else {                                  // partial last block
        for (int v = lane; v < WAVE_V4; v += 64)
            if (gbase + v < gmax) out4[gbase + v] = tile4[v];
    }
}

extern "C" void kernel_launch(void* const* d_in, const int* in_sizes, int n_in,
                              void* d_out, int out_size, void* d_ws, size_t ws_size,
                              hipStream_t stream) {
    const float* coords = (const float*)d_in[0];
    f32x4* out4 = (f32x4*)d_out;

    const int n_points = in_sizes[0] / 3;                        // 2,097,152
    const int grid = (n_points + WAVE_PTS - 1) / WAVE_PTS;       // 32768

    posenc_kernel<<<grid, BLOCK_THREADS, 0, stream>>>(coords, out4, n_points);
}